// Round 3
// baseline (2595.356 us; speedup 1.0000x reference)
//
#include <hip/hip_runtime.h>

// Fused 2-layer GRU scan, persistent kernel, single-barrier pipelined.
// B=256,T=1024,F=64,U=128. 16 blocks x 256 threads (4 waves = 1 wave/SIMD ->
// register budget ~512/thread; weights MUST stay register/AGPR resident, the
// R1/R2 2.1ms plateau was weight-frag spill-to-scratch reload at 512thr/2waves).
// Wave w owns 32 unit cols (2 groups of 16). Layer 2 runs one step delayed:
// iter t computes h1(t) and h2(t-1) -> ONE barrier/step; U1 and W2 share the
// same h1(t-1) A-frags (read once). x comes straight from global, prefetched.

#define TT 1024
#define FF 64
#define G3 384

typedef __attribute__((ext_vector_type(8))) __bf16 bf16x8;
typedef __attribute__((ext_vector_type(4))) float f32x4;

#define MFMA(a, b, c) __builtin_amdgcn_mfma_f32_16x16x32_bf16((a), (b), (c), 0, 0, 0)

__device__ __forceinline__ float sigf(float x) { return 1.0f / (1.0f + __expf(-x)); }

__global__ __launch_bounds__(256, 1) void gru_fused(
    const float* __restrict__ x,   // [B,T,F]
    const float* __restrict__ W1,  // [F,3U]
    const float* __restrict__ U1,  // [U,3U]
    const float* __restrict__ b1,  // [2,3U]
    const float* __restrict__ W2,  // [U,3U]
    const float* __restrict__ U2,  // [U,3U]
    const float* __restrict__ b2,  // [2,3U]
    float* __restrict__ out)       // [x(256x128), state1, state2] fp32
{
    const int tid  = threadIdx.x;
    const int wave = tid >> 6;          // 0..3
    const int lane = tid & 63;
    const int quad = lane >> 4;
    const int lc   = lane & 15;         // A row / C col index
    const int row0 = blockIdx.x * 16;

    // LDS: only h state, double-buffered. stride 136: b128-aligned, read
    // banks balanced (4*(lc+quad) mod 32, 8 lanes per 4-bank window = 8cyc min).
    __shared__ __align__(16) __bf16 h1s[2][16][136];
    __shared__ __align__(16) __bf16 h2s[2][16][136];

    for (int i = tid; i < 2 * 16 * 136; i += 256) {
        ((__bf16*)h1s)[i] = (__bf16)0.f;
        ((__bf16*)h2s)[i] = (__bf16)0.f;
    }

    // Weight B-frags, register/AGPR resident. 84 frags = 336 regs.
    // B-frag (16x16x32): lane holds B[k = kt*32 + quad*8 + j][col]
    // group gg col: u = wave*32 + gg*16 + lc
    bf16x8 W1B[2][3][2];
    bf16x8 U1B[2][3][4], W2B[2][3][4], U2B[2][3][4];
#pragma unroll
    for (int gg = 0; gg < 2; gg++) {
        const int col0 = wave * 32 + gg * 16 + lc;
#pragma unroll
        for (int g = 0; g < 3; g++) {
#pragma unroll
            for (int kt = 0; kt < 2; kt++) {
                bf16x8 a;
#pragma unroll
                for (int j = 0; j < 8; j++)
                    a[j] = (__bf16)W1[(kt * 32 + quad * 8 + j) * G3 + g * 128 + col0];
                W1B[gg][g][kt] = a;
            }
#pragma unroll
            for (int kt = 0; kt < 4; kt++) {
                bf16x8 a, b, c;
#pragma unroll
                for (int j = 0; j < 8; j++) {
                    int k = (kt * 32 + quad * 8 + j) * G3 + g * 128 + col0;
                    a[j] = (__bf16)U1[k];
                    b[j] = (__bf16)W2[k];
                    c[j] = (__bf16)U2[k];
                }
                U1B[gg][g][kt] = a; W2B[gg][g][kt] = b; U2B[gg][g][kt] = c;
            }
        }
    }

    // Biases per group (zero here, honored anyway); z/r input+recurrent fold.
    float c1z[2], c1r[2], b1ih[2], b1rh[2], c2z[2], c2r[2], b2ih[2], b2rh[2];
#pragma unroll
    for (int gg = 0; gg < 2; gg++) {
        const int u = wave * 32 + gg * 16 + lc;
        c1z[gg]  = b1[u] + b1[G3 + u];
        c1r[gg]  = b1[128 + u] + b1[G3 + 128 + u];
        b1ih[gg] = b1[256 + u];
        b1rh[gg] = b1[G3 + 256 + u];
        c2z[gg]  = b2[u] + b2[G3 + u];
        c2r[gg]  = b2[128 + u] + b2[G3 + 128 + u];
        b2ih[gg] = b2[256 + u];
        b2rh[gg] = b2[G3 + 256 + u];
    }

    // x A-frag source: lane (quad,lc) owns x[row0+lc][t][quad*8 .. +8] per kt
    const float* xrow = x + (size_t)(row0 + lc) * (TT * FF) + quad * 8;

    bf16x8 xa0, xa1;
    {
        f32x4 f0 = *(const f32x4*)(xrow);
        f32x4 f1 = *(const f32x4*)(xrow + 4);
        f32x4 f2 = *(const f32x4*)(xrow + 32);
        f32x4 f3 = *(const f32x4*)(xrow + 36);
#pragma unroll
        for (int j = 0; j < 4; j++) {
            xa0[j] = (__bf16)f0[j]; xa0[j + 4] = (__bf16)f1[j];
            xa1[j] = (__bf16)f2[j]; xa1[j + 4] = (__bf16)f3[j];
        }
    }

    float h1c[2][4] = {{0.f,0.f,0.f,0.f},{0.f,0.f,0.f,0.f}};
    float h2c[2][4] = {{0.f,0.f,0.f,0.f},{0.f,0.f,0.f,0.f}};

    __syncthreads();

    for (int t = 0; t < TT; t++) {
        // issue x(t+1) global loads (consumed at cvt point, latency hidden)
        f32x4 nf0, nf1, nf2, nf3;
        if (t + 1 < TT) {
            const float* p = xrow + (size_t)(t + 1) * FF;
            nf0 = *(const f32x4*)(p);
            nf1 = *(const f32x4*)(p + 4);
            nf2 = *(const f32x4*)(p + 32);
            nf3 = *(const f32x4*)(p + 36);
        }

        // issue A1 = h1(t-1) reads up front (latency hidden under ph1 MFMAs)
        bf16x8 A1[4];
#pragma unroll
        for (int kt = 0; kt < 4; kt++)
            A1[kt] = *(const bf16x8*)&h1s[(t + 1) & 1][lc][kt * 32 + quad * 8];

        // ph1: xw1 = x(t)@W1 (+bias C-init)
        f32x4 z1[2], r1[2], xh1[2], rh1[2];
#pragma unroll
        for (int gg = 0; gg < 2; gg++) {
            z1[gg]  = (f32x4){c1z[gg], c1z[gg], c1z[gg], c1z[gg]};
            r1[gg]  = (f32x4){c1r[gg], c1r[gg], c1r[gg], c1r[gg]};
            xh1[gg] = (f32x4){b1ih[gg], b1ih[gg], b1ih[gg], b1ih[gg]};
            rh1[gg] = (f32x4){b1rh[gg], b1rh[gg], b1rh[gg], b1rh[gg]};
            z1[gg]  = MFMA(xa0, W1B[gg][0][0], z1[gg]);
            z1[gg]  = MFMA(xa1, W1B[gg][0][1], z1[gg]);
            r1[gg]  = MFMA(xa0, W1B[gg][1][0], r1[gg]);
            r1[gg]  = MFMA(xa1, W1B[gg][1][1], r1[gg]);
            xh1[gg] = MFMA(xa0, W1B[gg][2][0], xh1[gg]);
            xh1[gg] = MFMA(xa1, W1B[gg][2][1], xh1[gg]);
        }

        // ph2: layer1 recurrent (A1 also reused by layer2's W2 below)
#pragma unroll
        for (int kt = 0; kt < 4; kt++)
#pragma unroll
            for (int gg = 0; gg < 2; gg++) {
                z1[gg]  = MFMA(A1[kt], U1B[gg][0][kt], z1[gg]);
                r1[gg]  = MFMA(A1[kt], U1B[gg][1][kt], r1[gg]);
                rh1[gg] = MFMA(A1[kt], U1B[gg][2][kt], rh1[gg]);
            }

        // ph3: layer1 gates + publish h1(t)
#pragma unroll
        for (int gg = 0; gg < 2; gg++) {
            const int u = wave * 32 + gg * 16 + lc;
#pragma unroll
            for (int i = 0; i < 4; i++) {
                float zf = sigf(z1[gg][i]);
                float rf = sigf(r1[gg][i]);
                float hh = fmaxf(xh1[gg][i] + rf * rh1[gg][i], 0.f);
                h1c[gg][i] = zf * h1c[gg][i] + (1.f - zf) * hh;
                h1s[t & 1][quad * 4 + i][u] = (__bf16)h1c[gg][i];
            }
        }

        // cvt x(t+1) (global loads drained; xa regs free after ph1)
        if (t + 1 < TT) {
#pragma unroll
            for (int j = 0; j < 4; j++) {
                xa0[j] = (__bf16)nf0[j]; xa0[j + 4] = (__bf16)nf1[j];
                xa1[j] = (__bf16)nf2[j]; xa1[j + 4] = (__bf16)nf3[j];
            }
        }

        // ph4: layer2 (one step delayed): xw2 = h1(t-1)@W2 (A1 reuse),
        //      rec2 = h2(t-2)@U2. A2 read deferred here to cap live regs.
        f32x4 z2[2], r2[2], xh2[2], rh2[2];
#pragma unroll
        for (int gg = 0; gg < 2; gg++) {
            z2[gg]  = (f32x4){c2z[gg], c2z[gg], c2z[gg], c2z[gg]};
            r2[gg]  = (f32x4){c2r[gg], c2r[gg], c2r[gg], c2r[gg]};
            xh2[gg] = (f32x4){b2ih[gg], b2ih[gg], b2ih[gg], b2ih[gg]};
            rh2[gg] = (f32x4){b2rh[gg], b2rh[gg], b2rh[gg], b2rh[gg]};
        }
        bf16x8 A2[4];
#pragma unroll
        for (int kt = 0; kt < 4; kt++)
            A2[kt] = *(const bf16x8*)&h2s[t & 1][lc][kt * 32 + quad * 8];
#pragma unroll
        for (int kt = 0; kt < 4; kt++)
#pragma unroll
            for (int gg = 0; gg < 2; gg++) {
                z2[gg]  = MFMA(A1[kt], W2B[gg][0][kt], z2[gg]);
                r2[gg]  = MFMA(A1[kt], W2B[gg][1][kt], r2[gg]);
                xh2[gg] = MFMA(A1[kt], W2B[gg][2][kt], xh2[gg]);
            }
#pragma unroll
        for (int kt = 0; kt < 4; kt++)
#pragma unroll
            for (int gg = 0; gg < 2; gg++) {
                z2[gg]  = MFMA(A2[kt], U2B[gg][0][kt], z2[gg]);
                r2[gg]  = MFMA(A2[kt], U2B[gg][1][kt], r2[gg]);
                rh2[gg] = MFMA(A2[kt], U2B[gg][2][kt], rh2[gg]);
            }
        if (t > 0) {
#pragma unroll
            for (int gg = 0; gg < 2; gg++)
#pragma unroll
                for (int i = 0; i < 4; i++) {
                    float zf = sigf(z2[gg][i]);
                    float rf = sigf(r2[gg][i]);
                    float hh = fmaxf(xh2[gg][i] + rf * rh2[gg][i], 0.f);
                    h2c[gg][i] = zf * h2c[gg][i] + (1.f - zf) * hh;
                }
        }
#pragma unroll
        for (int gg = 0; gg < 2; gg++) {
            const int u = wave * 32 + gg * 16 + lc;
#pragma unroll
            for (int i = 0; i < 4; i++)
                h2s[(t + 1) & 1][quad * 4 + i][u] = (__bf16)h2c[gg][i];
        }

        __syncthreads(); // the ONLY barrier per step
    }

    // Epilogue: h2(T-1) from h1(T-1) (h1s[(T-1)&1]) and h2(T-2) (h2s[T&1])
    {
        f32x4 z2[2], r2[2], xh2[2], rh2[2];
#pragma unroll
        for (int gg = 0; gg < 2; gg++) {
            z2[gg]  = (f32x4){c2z[gg], c2z[gg], c2z[gg], c2z[gg]};
            r2[gg]  = (f32x4){c2r[gg], c2r[gg], c2r[gg], c2r[gg]};
            xh2[gg] = (f32x4){b2ih[gg], b2ih[gg], b2ih[gg], b2ih[gg]};
            rh2[gg] = (f32x4){b2rh[gg], b2rh[gg], b2rh[gg], b2rh[gg]};
        }
#pragma unroll
        for (int kt = 0; kt < 4; kt++) {
            bf16x8 a1 = *(const bf16x8*)&h1s[(TT - 1) & 1][lc][kt * 32 + quad * 8];
            bf16x8 a2 = *(const bf16x8*)&h2s[TT & 1][lc][kt * 32 + quad * 8];
#pragma unroll
            for (int gg = 0; gg < 2; gg++) {
                z2[gg]  = MFMA(a1, W2B[gg][0][kt], z2[gg]);
                r2[gg]  = MFMA(a1, W2B[gg][1][kt], r2[gg]);
                xh2[gg] = MFMA(a1, W2B[gg][2][kt], xh2[gg]);
                z2[gg]  = MFMA(a2, U2B[gg][0][kt], z2[gg]);
                r2[gg]  = MFMA(a2, U2B[gg][1][kt], r2[gg]);
                rh2[gg] = MFMA(a2, U2B[gg][2][kt], rh2[gg]);
            }
        }
#pragma unroll
        for (int gg = 0; gg < 2; gg++)
#pragma unroll
            for (int i = 0; i < 4; i++) {
                float zf = sigf(z2[gg][i]);
                float rf = sigf(r2[gg][i]);
                float hh = fmaxf(xh2[gg][i] + rf * rh2[gg][i], 0.f);
                h2c[gg][i] = zf * h2c[gg][i] + (1.f - zf) * hh;
            }
    }

    // out = [x = h2(T-1), state1 = h1(T-1), state2 = h2(T-1)]
#pragma unroll
    for (int gg = 0; gg < 2; gg++) {
        const int u = wave * 32 + gg * 16 + lc;
#pragma unroll
        for (int i = 0; i < 4; i++) {
            int r = row0 + quad * 4 + i;
            out[(size_t)r * 128 + u]         = h2c[gg][i];
            out[32768 + (size_t)r * 128 + u] = h1c[gg][i];
            out[65536 + (size_t)r * 128 + u] = h2c[gg][i];
        }
    }
}

extern "C" void kernel_launch(void* const* d_in, const int* in_sizes, int n_in,
                              void* d_out, int out_size, void* d_ws, size_t ws_size,
                              hipStream_t stream) {
    const float* x  = (const float*)d_in[0];
    const float* W1 = (const float*)d_in[1];
    const float* U1 = (const float*)d_in[2];
    const float* b1 = (const float*)d_in[3];
    const float* W2 = (const float*)d_in[4];
    const float* U2 = (const float*)d_in[5];
    const float* b2 = (const float*)d_in[6];
    float* out = (float*)d_out;
    gru_fused<<<dim3(16), dim3(256), 0, stream>>>(x, W1, U1, b1, W2, U2, b2, out);
}

// Round 4
// 2461.072 us; speedup vs baseline: 1.0546x; 1.0546x over previous
//
#include <hip/hip_runtime.h>

// Fused 2-layer GRU scan. B=256,T=1024,F=64,U=128.
// R1-R3 post-mortem: all plateaued at ~2.2ms with active-CU VALUBusy ~60% --
// compiler rematerializes weight-frag global-load+cvt chains inside the step
// loop (occupancy-targeting scheduler). Fixes here:
//  1. asm volatile "+v" pins on all weight frags (remat impossible).
//  2. xw1 = x@W1+b_i precomputed to d_ws (bf16) by an MFMA prepass ->
//     persistent kernel keeps only U1/W2/U2 (36 frags = 144 VGPR) resident.
//  3. LDS-only barrier (s_waitcnt lgkmcnt(0); s_barrier) -- no vmcnt drain,
//     xw prefetch (distance 2) stays in flight across steps.
// 16 blocks x 512 threads; wave w owns unit cols [16w,16w+16). Layer 2 one
// step delayed => single barrier/step; U1 and W2 share the h1(t-1) A-frags.

#define TT 1024
#define FF 64
#define G3 384
#define XW_ELEMS (1024ull * 128 * 3 * 256)
#define XW_BYTES (XW_ELEMS * 2)

typedef __attribute__((ext_vector_type(8))) __bf16 bf16x8;
typedef __attribute__((ext_vector_type(4))) float f32x4;
typedef __attribute__((ext_vector_type(4))) int i32x4;

#define MFMA(a, b, c) __builtin_amdgcn_mfma_f32_16x16x32_bf16((a), (b), (c), 0, 0, 0)
#define BCAST(w) __builtin_bit_cast(bf16x8, w)

__device__ __forceinline__ float sigf(float x) {
    return __builtin_amdgcn_rcpf(1.0f + __expf(-x));
}

__device__ __forceinline__ void unpack4(uint2 v, float* o) {
    o[0] = __uint_as_float(v.x << 16);
    o[1] = __uint_as_float(v.x & 0xFFFF0000u);
    o[2] = __uint_as_float(v.y << 16);
    o[3] = __uint_as_float(v.y & 0xFFFF0000u);
}

// ---------------- prepass: xw[t][u][g][r] = (x@W1 + b1_input), bf16 ----------
__global__ __launch_bounds__(256) void xw_prepass(
    const float* __restrict__ x, const float* __restrict__ W1,
    const float* __restrict__ b1, unsigned short* __restrict__ ws)
{
    const int tid = threadIdx.x, wave = tid >> 6, lane = tid & 63;
    const int quad = lane >> 4, lc = lane & 15;
    const int rb = blockIdx.x;              // row block (16 rows)
    const int t  = blockIdx.y * 4 + wave;   // time step

    const float* px = x + ((size_t)(rb * 16 + lc) * TT + t) * FF + quad * 8;
    f32x4 u0 = *(const f32x4*)px;
    f32x4 u1 = *(const f32x4*)(px + 4);
    f32x4 u2 = *(const f32x4*)(px + 32);
    f32x4 u3 = *(const f32x4*)(px + 36);
    bf16x8 xa0, xa1;
#pragma unroll
    for (int j = 0; j < 4; j++) {
        xa0[j] = (__bf16)u0[j]; xa0[j + 4] = (__bf16)u1[j];
        xa1[j] = (__bf16)u2[j]; xa1[j + 4] = (__bf16)u3[j];
    }

    for (int nt = 0; nt < 24; nt++) {
        const int g = nt >> 3;
        const int uc = (nt & 7) * 16 + lc;
        const float bi = b1[g * 128 + uc];
        bf16x8 w0, w1v;
#pragma unroll
        for (int j = 0; j < 8; j++) {
            w0[j]  = (__bf16)W1[(quad * 8 + j) * G3 + g * 128 + uc];
            w1v[j] = (__bf16)W1[(32 + quad * 8 + j) * G3 + g * 128 + uc];
        }
        f32x4 acc = {bi, bi, bi, bi};
        acc = MFMA(xa0, w0, acc);
        acc = MFMA(xa1, w1v, acc);
        unsigned int s0 = __builtin_bit_cast(unsigned short, (__bf16)acc[0]);
        unsigned int s1 = __builtin_bit_cast(unsigned short, (__bf16)acc[1]);
        unsigned int s2 = __builtin_bit_cast(unsigned short, (__bf16)acc[2]);
        unsigned int s3 = __builtin_bit_cast(unsigned short, (__bf16)acc[3]);
        uint2 st;
        st.x = s0 | (s1 << 16);
        st.y = s2 | (s3 << 16);
        *(uint2*)(ws + ((size_t)(t * 128 + uc) * 3 + g) * 256 + rb * 16 + quad * 4) = st;
    }
}

// ---------------- persistent scan kernel ------------------------------------
template <bool PRE>
__global__ __launch_bounds__(512, 2) void gru_persist(
    const float* __restrict__ x,  const float* __restrict__ W1,
    const float* __restrict__ U1, const float* __restrict__ b1,
    const float* __restrict__ W2, const float* __restrict__ U2,
    const float* __restrict__ b2, const unsigned short* __restrict__ xw,
    float* __restrict__ out)
{
    const int tid  = threadIdx.x;
    const int wave = tid >> 6;          // 0..7
    const int lane = tid & 63;
    const int quad = lane >> 4;
    const int lc   = lane & 15;
    const int u    = wave * 16 + lc;    // unit column 0..127
    const int row0 = blockIdx.x * 16;

    __shared__ __align__(16) __bf16 h1s[2][16][136];
    __shared__ __align__(16) __bf16 h2s[2][16][136];
    for (int i = tid; i < 2 * 16 * 136; i += 512) {
        ((__bf16*)h1s)[i] = (__bf16)0.f;
        ((__bf16*)h2s)[i] = (__bf16)0.f;
    }

    // ---- weight fragments: load once, PIN in VGPRs (anti-remat) ----
    i32x4 U1B[3][4], W2B[3][4], U2B[3][4];
    i32x4 W1B[3][2];
#pragma unroll
    for (int g = 0; g < 3; g++) {
#pragma unroll
        for (int kt = 0; kt < 4; kt++) {
            bf16x8 a, b, c;
#pragma unroll
            for (int j = 0; j < 8; j++) {
                int k = (kt * 32 + quad * 8 + j) * G3 + g * 128 + u;
                a[j] = (__bf16)U1[k];
                b[j] = (__bf16)W2[k];
                c[j] = (__bf16)U2[k];
            }
            U1B[g][kt] = __builtin_bit_cast(i32x4, a);
            W2B[g][kt] = __builtin_bit_cast(i32x4, b);
            U2B[g][kt] = __builtin_bit_cast(i32x4, c);
        }
        if constexpr (!PRE) {
#pragma unroll
            for (int kt = 0; kt < 2; kt++) {
                bf16x8 a;
#pragma unroll
                for (int j = 0; j < 8; j++)
                    a[j] = (__bf16)W1[(kt * 32 + quad * 8 + j) * G3 + g * 128 + u];
                W1B[g][kt] = __builtin_bit_cast(i32x4, a);
            }
        }
    }
#pragma unroll
    for (int g = 0; g < 3; g++)
#pragma unroll
        for (int kt = 0; kt < 4; kt++)
            asm volatile("" : "+v"(U1B[g][kt]), "+v"(W2B[g][kt]), "+v"(U2B[g][kt]));
    if constexpr (!PRE) {
#pragma unroll
        for (int g = 0; g < 3; g++)
#pragma unroll
            for (int kt = 0; kt < 2; kt++)
                asm volatile("" : "+v"(W1B[g][kt]));
    }

    // ---- biases (zeros in this problem; honored) ----
    float c1z, c1r;
    if constexpr (PRE) {            // input bias already folded into xw
        c1z = b1[G3 + u];
        c1r = b1[G3 + 128 + u];
    } else {
        c1z = b1[u] + b1[G3 + u];
        c1r = b1[128 + u] + b1[G3 + 128 + u];
    }
    const float b1ih = b1[256 + u];         // used only when !PRE
    const float b1rh = b1[G3 + 256 + u];
    const float c2z  = b2[u] + b2[G3 + u];
    const float c2r  = b2[128 + u] + b2[G3 + 128 + u];
    const float b2ih = b2[256 + u];
    const float b2rh = b2[G3 + 256 + u];

    // ---- xw prefetch (PRE) / x source (!PRE) ----
    const unsigned short* xwp = xw + u * 768 + row0 + quad * 4;
    uint2 xwv[2][3];
    if constexpr (PRE) {
#pragma unroll
        for (int g = 0; g < 3; g++) {
            xwv[0][g] = *(const uint2*)(xwp + g * 256);
            xwv[1][g] = *(const uint2*)(xwp + 98304 + g * 256);
        }
    }
    const float* xrow = x + (size_t)(row0 + lc) * (TT * FF) + quad * 8;

    float h1c[4] = {0.f, 0.f, 0.f, 0.f};
    float h2c[4] = {0.f, 0.f, 0.f, 0.f};

    __syncthreads();

#define STEP(T, PAR)                                                           \
    {                                                                          \
        bf16x8 A1[4];                                                          \
        _Pragma("unroll") for (int kt = 0; kt < 4; kt++)                       \
            A1[kt] = *(const bf16x8*)&h1s[PAR ^ 1][lc][kt * 32 + quad * 8];    \
        float xz[4], xr[4], xh[4];                                             \
        bf16x8 xa0, xa1;                                                       \
        if constexpr (PRE) {                                                   \
            unpack4(xwv[PAR][0], xz);                                          \
            unpack4(xwv[PAR][1], xr);                                          \
            unpack4(xwv[PAR][2], xh);                                          \
            if ((T) + 2 < TT) {                                                \
                const unsigned short* p = xwp + (size_t)((T) + 2) * 98304;     \
                _Pragma("unroll") for (int g = 0; g < 3; g++)                  \
                    xwv[PAR][g] = *(const uint2*)(p + g * 256);                \
            }                                                                  \
        } else {                                                               \
            const float* px = xrow + (size_t)(T) * FF;                         \
            f32x4 u0 = *(const f32x4*)px;                                      \
            f32x4 u1 = *(const f32x4*)(px + 4);                                \
            f32x4 u2 = *(const f32x4*)(px + 32);                               \
            f32x4 u3 = *(const f32x4*)(px + 36);                               \
            _Pragma("unroll") for (int j = 0; j < 4; j++) {                    \
                xa0[j] = (__bf16)u0[j]; xa0[j + 4] = (__bf16)u1[j];            \
                xa1[j] = (__bf16)u2[j]; xa1[j + 4] = (__bf16)u3[j];            \
            }                                                                  \
        }                                                                      \
        f32x4 z1  = {c1z, c1z, c1z, c1z};                                      \
        f32x4 r1  = {c1r, c1r, c1r, c1r};                                      \
        f32x4 rh1 = {b1rh, b1rh, b1rh, b1rh};                                  \
        f32x4 xh1 = {b1ih, b1ih, b1ih, b1ih};                                  \
        if constexpr (PRE) {                                                   \
            z1[0] += xz[0]; z1[1] += xz[1]; z1[2] += xz[2]; z1[3] += xz[3];    \
            r1[0] += xr[0]; r1[1] += xr[1]; r1[2] += xr[2]; r1[3] += xr[3];    \
        } else {                                                               \
            z1  = MFMA(xa0, BCAST(W1B[0][0]), z1);                             \
            z1  = MFMA(xa1, BCAST(W1B[0][1]), z1);                             \
            r1  = MFMA(xa0, BCAST(W1B[1][0]), r1);                             \
            r1  = MFMA(xa1, BCAST(W1B[1][1]), r1);                             \
            xh1 = MFMA(xa0, BCAST(W1B[2][0]), xh1);                            \
            xh1 = MFMA(xa1, BCAST(W1B[2][1]), xh1);                            \
        }                                                                      \
        _Pragma("unroll") for (int kt = 0; kt < 4; kt++) {                     \
            z1  = MFMA(A1[kt], BCAST(U1B[0][kt]), z1);                         \
            r1  = MFMA(A1[kt], BCAST(U1B[1][kt]), r1);                         \
            rh1 = MFMA(A1[kt], BCAST(U1B[2][kt]), rh1);                        \
        }                                                                      \
        f32x4 z2  = {c2z, c2z, c2z, c2z};                                      \
        f32x4 r2  = {c2r, c2r, c2r, c2r};                                      \
        f32x4 xh2 = {b2ih, b2ih, b2ih, b2ih};                                  \
        f32x4 rh2 = {b2rh, b2rh, b2rh, b2rh};                                  \
        _Pragma("unroll") for (int kt = 0; kt < 4; kt++) {                     \
            z2  = MFMA(A1[kt], BCAST(W2B[0][kt]), z2);                         \
            r2  = MFMA(A1[kt], BCAST(W2B[1][kt]), r2);                         \
            xh2 = MFMA(A1[kt], BCAST(W2B[2][kt]), xh2);                        \
        }                                                                      \
        bf16x8 A2[4];                                                          \
        _Pragma("unroll") for (int kt = 0; kt < 4; kt++)                       \
            A2[kt] = *(const bf16x8*)&h2s[PAR][lc][kt * 32 + quad * 8];        \
        _Pragma("unroll") for (int kt = 0; kt < 4; kt++) {                     \
            z2  = MFMA(A2[kt], BCAST(U2B[0][kt]), z2);                         \
            r2  = MFMA(A2[kt], BCAST(U2B[1][kt]), r2);                         \
            rh2 = MFMA(A2[kt], BCAST(U2B[2][kt]), rh2);                        \
        }                                                                      \
        _Pragma("unroll") for (int i = 0; i < 4; i++) {                        \
            float zf = sigf(z1[i]);                                            \
            float rf = sigf(r1[i]);                                            \
            float xhv = PRE ? xh[i] : xh1[i];                                  \
            float hh = fmaxf(xhv + rf * rh1[i], 0.f);                          \
            h1c[i] = fmaf(zf, h1c[i] - hh, hh);                                \
            h1s[PAR][quad * 4 + i][u] = (__bf16)h1c[i];                        \
        }                                                                      \
        if ((T) > 0) {                                                         \
            _Pragma("unroll") for (int i = 0; i < 4; i++) {                    \
                float zf = sigf(z2[i]);                                        \
                float rf = sigf(r2[i]);                                        \
                float hh = fmaxf(xh2[i] + rf * rh2[i], 0.f);                   \
                h2c[i] = fmaf(zf, h2c[i] - hh, hh);                            \
            }                                                                  \
        }                                                                      \
        _Pragma("unroll") for (int i = 0; i < 4; i++)                          \
            h2s[PAR ^ 1][quad * 4 + i][u] = (__bf16)h2c[i];                    \
        asm volatile("s_waitcnt lgkmcnt(0)\n\ts_barrier" ::: "memory");        \
    }

    for (int t = 0; t < TT; t += 2) {
        STEP(t, 0)
        STEP(t + 1, 1)
    }
#undef STEP

    // Epilogue half-step: h2(TT-1) from h1(TT-1) (h1s[1]) and h2(TT-2) (h2s[0])
    {
        f32x4 z2  = {c2z, c2z, c2z, c2z};
        f32x4 r2  = {c2r, c2r, c2r, c2r};
        f32x4 xh2 = {b2ih, b2ih, b2ih, b2ih};
        f32x4 rh2 = {b2rh, b2rh, b2rh, b2rh};
#pragma unroll
        for (int kt = 0; kt < 4; kt++) {
            bf16x8 a1 = *(const bf16x8*)&h1s[1][lc][kt * 32 + quad * 8];
            bf16x8 a2 = *(const bf16x8*)&h2s[0][lc][kt * 32 + quad * 8];
            z2  = MFMA(a1, BCAST(W2B[0][kt]), z2);
            r2  = MFMA(a1, BCAST(W2B[1][kt]), r2);
            xh2 = MFMA(a1, BCAST(W2B[2][kt]), xh2);
            z2  = MFMA(a2, BCAST(U2B[0][kt]), z2);
            r2  = MFMA(a2, BCAST(U2B[1][kt]), r2);
            rh2 = MFMA(a2, BCAST(U2B[2][kt]), rh2);
        }
#pragma unroll
        for (int i = 0; i < 4; i++) {
            float zf = sigf(z2[i]);
            float rf = sigf(r2[i]);
            float hh = fmaxf(xh2[i] + rf * rh2[i], 0.f);
            h2c[i] = fmaf(zf, h2c[i] - hh, hh);
        }
    }

    // out = [x = h2(T-1), state1 = h1(T-1), state2 = h2(T-1)]
#pragma unroll
    for (int i = 0; i < 4; i++) {
        int r = row0 + quad * 4 + i;
        out[(size_t)r * 128 + u]         = h2c[i];
        out[32768 + (size_t)r * 128 + u] = h1c[i];
        out[65536 + (size_t)r * 128 + u] = h2c[i];
    }
}

extern "C" void kernel_launch(void* const* d_in, const int* in_sizes, int n_in,
                              void* d_out, int out_size, void* d_ws, size_t ws_size,
                              hipStream_t stream) {
    const float* x  = (const float*)d_in[0];
    const float* W1 = (const float*)d_in[1];
    const float* U1 = (const float*)d_in[2];
    const float* b1 = (const float*)d_in[3];
    const float* W2 = (const float*)d_in[4];
    const float* U2 = (const float*)d_in[5];
    const float* b2 = (const float*)d_in[6];
    float* out = (float*)d_out;

    if (ws_size >= XW_BYTES) {
        unsigned short* ws = (unsigned short*)d_ws;
        xw_prepass<<<dim3(16, 256), dim3(256), 0, stream>>>(x, W1, b1, ws);
        gru_persist<true><<<dim3(16), dim3(512), 0, stream>>>(
            x, W1, U1, b1, W2, U2, b2, ws, out);
    } else {
        gru_persist<false><<<dim3(16), dim3(512), 0, stream>>>(
            x, W1, U1, b1, W2, U2, b2, nullptr, out);
    }
}

// Round 5
// 2019.260 us; speedup vs baseline: 1.2853x; 1.2188x over previous
//
#include <hip/hip_runtime.h>

// Fused 2-layer GRU scan. B=256,T=1024,F=64,U=128.
// R1-R4 evidence: ~5100 cyc/step fixed floor, insensitive to LDS/VALU/MFMA
// reductions => memory-latency (spill/remat reload) on the per-step critical
// path. Root cause: unified VGPR+AGPR budget. At 512thr (2 waves/SIMD) budget
// is 256 regs/thread; weights(144)+working(~110) = cliff => spills. This
// round: 256 threads (1 wave/SIMD, 512-reg budget), PRE (W1 folded into a
// precomputed xw stream in d_ws), 2 column groups/wave: weights 288 regs +
// ~140 working = ~430 <= 512, pinned vs remat. xw layout made fully
// coalesced on both producer and consumer ([t][g][u][quad] uint2 chunks).

#define TT 1024
#define FF 64
#define G3 384
#define XW_BYTES (1024ull * 384 * 256 * 2)

typedef __attribute__((ext_vector_type(8))) __bf16 bf16x8;
typedef __attribute__((ext_vector_type(4))) float f32x4;
typedef __attribute__((ext_vector_type(4))) int i32x4;

#define MFMA(a, b, c) __builtin_amdgcn_mfma_f32_16x16x32_bf16((a), (b), (c), 0, 0, 0)
#define BCAST(w) __builtin_bit_cast(bf16x8, w)

__device__ __forceinline__ float sigf(float x) {
    return __builtin_amdgcn_rcpf(1.0f + __expf(-x));
}

__device__ __forceinline__ void unpack4(uint2 v, float* o) {
    o[0] = __uint_as_float(v.x << 16);
    o[1] = __uint_as_float(v.x & 0xFFFF0000u);
    o[2] = __uint_as_float(v.y << 16);
    o[3] = __uint_as_float(v.y & 0xFFFF0000u);
}

// ---- prepass: xw[(t*3+g)*128+u][quad] (uint2 = rows quad*4..+3) -----------
// = (x@W1 + b1_input) in bf16. Both write (here) and read (persist) are
// contiguous 512B per wave per (t,g).
__global__ void xw_prepass(
    const float* __restrict__ x, const float* __restrict__ W1,
    const float* __restrict__ b1, unsigned short* __restrict__ ws)
{
    const int tid = threadIdx.x, wave = tid >> 6, lane = tid & 63;
    const int quad = lane >> 4, lc = lane & 15;
    const int rb = blockIdx.x;              // row block (16 rows)
    const int t  = blockIdx.y * 4 + wave;   // time step

    const float* px = x + ((size_t)(rb * 16 + lc) * TT + t) * FF + quad * 8;
    f32x4 u0 = *(const f32x4*)px;
    f32x4 u1 = *(const f32x4*)(px + 4);
    f32x4 u2 = *(const f32x4*)(px + 32);
    f32x4 u3 = *(const f32x4*)(px + 36);
    bf16x8 xa0, xa1;
#pragma unroll
    for (int j = 0; j < 4; j++) {
        xa0[j] = (__bf16)u0[j]; xa0[j + 4] = (__bf16)u1[j];
        xa1[j] = (__bf16)u2[j]; xa1[j + 4] = (__bf16)u3[j];
    }

    for (int nt = 0; nt < 24; nt++) {
        const int g = nt >> 3;
        const int uc = (nt & 7) * 16 + lc;
        const float bi = b1[g * 128 + uc];
        bf16x8 w0, w1v;
#pragma unroll
        for (int j = 0; j < 8; j++) {
            w0[j]  = (__bf16)W1[(quad * 8 + j) * G3 + g * 128 + uc];
            w1v[j] = (__bf16)W1[(32 + quad * 8 + j) * G3 + g * 128 + uc];
        }
        f32x4 acc = {bi, bi, bi, bi};
        acc = MFMA(xa0, w0, acc);
        acc = MFMA(xa1, w1v, acc);
        unsigned int s0 = __builtin_bit_cast(unsigned short, (__bf16)acc[0]);
        unsigned int s1 = __builtin_bit_cast(unsigned short, (__bf16)acc[1]);
        unsigned int s2 = __builtin_bit_cast(unsigned short, (__bf16)acc[2]);
        unsigned int s3 = __builtin_bit_cast(unsigned short, (__bf16)acc[3]);
        uint2 st;
        st.x = s0 | (s1 << 16);
        st.y = s2 | (s3 << 16);
        // rows rb*16 interleave: each row block writes its own quadrant of B
        size_t q = (((size_t)t * 3 + g) * 128 + uc) * 64 + rb * 4 + quad;
        ((uint2*)ws)[q] = st;
    }
}

// ---- persistent scan kernel -----------------------------------------------
template <bool PRE>
__global__ __launch_bounds__(256, 1) void gru_persist(
    const float* __restrict__ x,  const float* __restrict__ W1,
    const float* __restrict__ U1, const float* __restrict__ b1,
    const float* __restrict__ W2, const float* __restrict__ U2,
    const float* __restrict__ b2, const unsigned short* __restrict__ xw,
    float* __restrict__ out)
{
    const int tid  = threadIdx.x;
    const int wave = tid >> 6;          // 0..3
    const int lane = tid & 63;
    const int quad = lane >> 4;
    const int lc   = lane & 15;
    const int row0 = blockIdx.x * 16;

    __shared__ __align__(16) __bf16 h1s[2][16][136];
    __shared__ __align__(16) __bf16 h2s[2][16][136];
    for (int i = tid; i < 2 * 16 * 136; i += 256) {
        ((__bf16*)h1s)[i] = (__bf16)0.f;
        ((__bf16*)h2s)[i] = (__bf16)0.f;
    }

    // ---- weight B-frags: 2 column groups/wave, pinned resident ----
    i32x4 U1B[2][3][4], W2B[2][3][4], U2B[2][3][4];
    i32x4 W1B[2][3][2];
#pragma unroll
    for (int gg = 0; gg < 2; gg++) {
        const int col0 = wave * 32 + gg * 16 + lc;
#pragma unroll
        for (int g = 0; g < 3; g++) {
#pragma unroll
            for (int kt = 0; kt < 4; kt++) {
                bf16x8 a, b, c;
#pragma unroll
                for (int j = 0; j < 8; j++) {
                    int k = (kt * 32 + quad * 8 + j) * G3 + g * 128 + col0;
                    a[j] = (__bf16)U1[k];
                    b[j] = (__bf16)W2[k];
                    c[j] = (__bf16)U2[k];
                }
                U1B[gg][g][kt] = __builtin_bit_cast(i32x4, a);
                W2B[gg][g][kt] = __builtin_bit_cast(i32x4, b);
                U2B[gg][g][kt] = __builtin_bit_cast(i32x4, c);
            }
            if constexpr (!PRE) {
#pragma unroll
                for (int kt = 0; kt < 2; kt++) {
                    bf16x8 a;
#pragma unroll
                    for (int j = 0; j < 8; j++)
                        a[j] = (__bf16)W1[(kt * 32 + quad * 8 + j) * G3 + g * 128 + col0];
                    W1B[gg][g][kt] = __builtin_bit_cast(i32x4, a);
                }
            }
        }
    }
#pragma unroll
    for (int gg = 0; gg < 2; gg++)
#pragma unroll
        for (int g = 0; g < 3; g++)
#pragma unroll
            for (int kt = 0; kt < 4; kt++)
                asm volatile("" : "+v"(U1B[gg][g][kt]), "+v"(W2B[gg][g][kt]),
                                  "+v"(U2B[gg][g][kt]));
    if constexpr (!PRE) {
#pragma unroll
        for (int gg = 0; gg < 2; gg++)
#pragma unroll
            for (int g = 0; g < 3; g++)
#pragma unroll
                for (int kt = 0; kt < 2; kt++)
                    asm volatile("" : "+v"(W1B[gg][g][kt]));
    }

    // ---- biases (zero here; honored) ----
    float c1z[2], c1r[2], b1ih[2], b1rh[2], c2z[2], c2r[2], b2ih[2], b2rh[2];
#pragma unroll
    for (int gg = 0; gg < 2; gg++) {
        const int u = wave * 32 + gg * 16 + lc;
        c1z[gg]  = PRE ? b1[G3 + u] : b1[u] + b1[G3 + u];
        c1r[gg]  = PRE ? b1[G3 + 128 + u] : b1[128 + u] + b1[G3 + 128 + u];
        b1ih[gg] = b1[256 + u];
        b1rh[gg] = b1[G3 + 256 + u];
        c2z[gg]  = b2[u] + b2[G3 + u];
        c2r[gg]  = b2[128 + u] + b2[G3 + 128 + u];
        b2ih[gg] = b2[256 + u];
        b2rh[gg] = b2[G3 + 256 + u];
    }

    // ---- xw bases (coalesced): q(t,g,gg) = t*1536*... see prepass ----
    const uint2* xq[2];
    uint2 xwv[2][2][3];   // [parity][gg][gate]
    if constexpr (PRE) {
#pragma unroll
        for (int gg = 0; gg < 2; gg++) {
            const int u = wave * 32 + gg * 16 + lc;
            xq[gg] = (const uint2*)xw + (size_t)u * 64 + blockIdx.x * 4 + quad;
#pragma unroll
            for (int g = 0; g < 3; g++) {
                xwv[0][gg][g] = xq[gg][(size_t)(0 * 3 + g) * 8192];
                xwv[1][gg][g] = xq[gg][(size_t)(1 * 3 + g) * 8192];
            }
        }
    }
    const float* xrow = x + (size_t)(row0 + lc) * (TT * FF) + quad * 8;

    float h1c[2][4] = {{0,0,0,0},{0,0,0,0}};
    float h2c[2][4] = {{0,0,0,0},{0,0,0,0}};

    __syncthreads();

#define STEP(T, PAR)                                                           \
    {                                                                          \
        bf16x8 A1[4];                                                          \
        _Pragma("unroll") for (int kt = 0; kt < 4; kt++)                       \
            A1[kt] = *(const bf16x8*)&h1s[PAR ^ 1][lc][kt * 32 + quad * 8];    \
        float xz[2][4], xr[2][4], xh[2][4];                                    \
        bf16x8 xa0, xa1;                                                       \
        if constexpr (PRE) {                                                   \
            _Pragma("unroll") for (int gg = 0; gg < 2; gg++) {                 \
                unpack4(xwv[PAR][gg][0], xz[gg]);                              \
                unpack4(xwv[PAR][gg][1], xr[gg]);                              \
                unpack4(xwv[PAR][gg][2], xh[gg]);                              \
            }                                                                  \
            if ((T) + 2 < TT) {                                                \
                _Pragma("unroll") for (int gg = 0; gg < 2; gg++)               \
                    _Pragma("unroll") for (int g = 0; g < 3; g++)              \
                        xwv[PAR][gg][g] =                                      \
                            xq[gg][(size_t)(((T) + 2) * 3 + g) * 8192];        \
            }                                                                  \
        } else {                                                               \
            const float* px = xrow + (size_t)(T) * FF;                         \
            f32x4 u0 = *(const f32x4*)px;                                      \
            f32x4 u1 = *(const f32x4*)(px + 4);                                \
            f32x4 u2 = *(const f32x4*)(px + 32);                               \
            f32x4 u3 = *(const f32x4*)(px + 36);                               \
            _Pragma("unroll") for (int j = 0; j < 4; j++) {                    \
                xa0[j] = (__bf16)u0[j]; xa0[j + 4] = (__bf16)u1[j];            \
                xa1[j] = (__bf16)u2[j]; xa1[j + 4] = (__bf16)u3[j];            \
            }                                                                  \
        }                                                                      \
        f32x4 z1[2], r1[2], rh1[2], xh1[2];                                    \
        _Pragma("unroll") for (int gg = 0; gg < 2; gg++) {                     \
            z1[gg]  = (f32x4){c1z[gg], c1z[gg], c1z[gg], c1z[gg]};             \
            r1[gg]  = (f32x4){c1r[gg], c1r[gg], c1r[gg], c1r[gg]};             \
            rh1[gg] = (f32x4){b1rh[gg], b1rh[gg], b1rh[gg], b1rh[gg]};         \
            xh1[gg] = (f32x4){b1ih[gg], b1ih[gg], b1ih[gg], b1ih[gg]};         \
            if constexpr (PRE) {                                               \
                _Pragma("unroll") for (int i = 0; i < 4; i++) {                \
                    z1[gg][i] += xz[gg][i];                                    \
                    r1[gg][i] += xr[gg][i];                                    \
                }                                                              \
            } else {                                                           \
                z1[gg]  = MFMA(xa0, BCAST(W1B[gg][0][0]), z1[gg]);             \
                z1[gg]  = MFMA(xa1, BCAST(W1B[gg][0][1]), z1[gg]);             \
                r1[gg]  = MFMA(xa0, BCAST(W1B[gg][1][0]), r1[gg]);             \
                r1[gg]  = MFMA(xa1, BCAST(W1B[gg][1][1]), r1[gg]);             \
                xh1[gg] = MFMA(xa0, BCAST(W1B[gg][2][0]), xh1[gg]);            \
                xh1[gg] = MFMA(xa1, BCAST(W1B[gg][2][1]), xh1[gg]);            \
            }                                                                  \
        }                                                                      \
        _Pragma("unroll") for (int kt = 0; kt < 4; kt++)                       \
            _Pragma("unroll") for (int gg = 0; gg < 2; gg++) {                 \
                z1[gg]  = MFMA(A1[kt], BCAST(U1B[gg][0][kt]), z1[gg]);         \
                r1[gg]  = MFMA(A1[kt], BCAST(U1B[gg][1][kt]), r1[gg]);         \
                rh1[gg] = MFMA(A1[kt], BCAST(U1B[gg][2][kt]), rh1[gg]);        \
            }                                                                  \
        _Pragma("unroll") for (int gg = 0; gg < 2; gg++) {                     \
            const int u = wave * 32 + gg * 16 + lc;                            \
            _Pragma("unroll") for (int i = 0; i < 4; i++) {                    \
                float zf = sigf(z1[gg][i]);                                    \
                float rf = sigf(r1[gg][i]);                                    \
                float xhv = PRE ? xh[gg][i] : xh1[gg][i];                      \
                float hh = fmaxf(xhv + rf * rh1[gg][i], 0.f);                  \
                h1c[gg][i] = fmaf(zf, h1c[gg][i] - hh, hh);                    \
                h1s[PAR][quad * 4 + i][u] = (__bf16)h1c[gg][i];                \
            }                                                                  \
        }                                                                      \
        f32x4 z2[2], r2[2], xh2[2], rh2[2];                                    \
        _Pragma("unroll") for (int gg = 0; gg < 2; gg++) {                     \
            z2[gg]  = (f32x4){c2z[gg], c2z[gg], c2z[gg], c2z[gg]};             \
            r2[gg]  = (f32x4){c2r[gg], c2r[gg], c2r[gg], c2r[gg]};             \
            xh2[gg] = (f32x4){b2ih[gg], b2ih[gg], b2ih[gg], b2ih[gg]};         \
            rh2[gg] = (f32x4){b2rh[gg], b2rh[gg], b2rh[gg], b2rh[gg]};         \
        }                                                                      \
        _Pragma("unroll") for (int kt = 0; kt < 4; kt++)                       \
            _Pragma("unroll") for (int gg = 0; gg < 2; gg++) {                 \
                z2[gg]  = MFMA(A1[kt], BCAST(W2B[gg][0][kt]), z2[gg]);         \
                r2[gg]  = MFMA(A1[kt], BCAST(W2B[gg][1][kt]), r2[gg]);         \
                xh2[gg] = MFMA(A1[kt], BCAST(W2B[gg][2][kt]), xh2[gg]);        \
            }                                                                  \
        bf16x8 A2[4];                                                          \
        _Pragma("unroll") for (int kt = 0; kt < 4; kt++)                       \
            A2[kt] = *(const bf16x8*)&h2s[PAR][lc][kt * 32 + quad * 8];        \
        _Pragma("unroll") for (int kt = 0; kt < 4; kt++)                       \
            _Pragma("unroll") for (int gg = 0; gg < 2; gg++) {                 \
                z2[gg]  = MFMA(A2[kt], BCAST(U2B[gg][0][kt]), z2[gg]);         \
                r2[gg]  = MFMA(A2[kt], BCAST(U2B[gg][1][kt]), r2[gg]);         \
                rh2[gg] = MFMA(A2[kt], BCAST(U2B[gg][2][kt]), rh2[gg]);        \
            }                                                                  \
        if ((T) > 0) {                                                         \
            _Pragma("unroll") for (int gg = 0; gg < 2; gg++)                   \
                _Pragma("unroll") for (int i = 0; i < 4; i++) {                \
                    float zf = sigf(z2[gg][i]);                                \
                    float rf = sigf(r2[gg][i]);                                \
                    float hh = fmaxf(xh2[gg][i] + rf * rh2[gg][i], 0.f);       \
                    h2c[gg][i] = fmaf(zf, h2c[gg][i] - hh, hh);                \
                }                                                              \
        }                                                                      \
        _Pragma("unroll") for (int gg = 0; gg < 2; gg++) {                     \
            const int u = wave * 32 + gg * 16 + lc;                            \
            _Pragma("unroll") for (int i = 0; i < 4; i++)                      \
                h2s[PAR ^ 1][quad * 4 + i][u] = (__bf16)h2c[gg][i];            \
        }                                                                      \
        asm volatile("s_waitcnt lgkmcnt(0)\n\ts_barrier" ::: "memory");        \
    }

    for (int t = 0; t < TT; t += 2) {
        STEP(t, 0)
        STEP(t + 1, 1)
    }
#undef STEP

    // Epilogue: h2(TT-1) from h1(TT-1) (h1s[1]) and h2(TT-2) (h2s[0])
    {
        f32x4 z2[2], r2[2], xh2[2], rh2[2];
#pragma unroll
        for (int gg = 0; gg < 2; gg++) {
            z2[gg]  = (f32x4){c2z[gg], c2z[gg], c2z[gg], c2z[gg]};
            r2[gg]  = (f32x4){c2r[gg], c2r[gg], c2r[gg], c2r[gg]};
            xh2[gg] = (f32x4){b2ih[gg], b2ih[gg], b2ih[gg], b2ih[gg]};
            rh2[gg] = (f32x4){b2rh[gg], b2rh[gg], b2rh[gg], b2rh[gg]};
        }
#pragma unroll
        for (int kt = 0; kt < 4; kt++) {
            bf16x8 a1 = *(const bf16x8*)&h1s[1][lc][kt * 32 + quad * 8];
            bf16x8 a2 = *(const bf16x8*)&h2s[0][lc][kt * 32 + quad * 8];
#pragma unroll
            for (int gg = 0; gg < 2; gg++) {
                z2[gg]  = MFMA(a1, BCAST(W2B[gg][0][kt]), z2[gg]);
                r2[gg]  = MFMA(a1, BCAST(W2B[gg][1][kt]), r2[gg]);
                xh2[gg] = MFMA(a1, BCAST(W2B[gg][2][kt]), xh2[gg]);
                z2[gg]  = MFMA(a2, BCAST(U2B[gg][0][kt]), z2[gg]);
                r2[gg]  = MFMA(a2, BCAST(U2B[gg][1][kt]), r2[gg]);
                rh2[gg] = MFMA(a2, BCAST(U2B[gg][2][kt]), rh2[gg]);
            }
        }
#pragma unroll
        for (int gg = 0; gg < 2; gg++)
#pragma unroll
            for (int i = 0; i < 4; i++) {
                float zf = sigf(z2[gg][i]);
                float rf = sigf(r2[gg][i]);
                float hh = fmaxf(xh2[gg][i] + rf * rh2[gg][i], 0.f);
                h2c[gg][i] = fmaf(zf, h2c[gg][i] - hh, hh);
            }
    }

    // out = [x = h2(T-1), state1 = h1(T-1), state2 = h2(T-1)]
#pragma unroll
    for (int gg = 0; gg < 2; gg++) {
        const int u = wave * 32 + gg * 16 + lc;
#pragma unroll
        for (int i = 0; i < 4; i++) {
            int r = row0 + quad * 4 + i;
            out[(size_t)r * 128 + u]         = h2c[gg][i];
            out[32768 + (size_t)r * 128 + u] = h1c[gg][i];
            out[65536 + (size_t)r * 128 + u] = h2c[gg][i];
        }
    }
}

extern "C" void kernel_launch(void* const* d_in, const int* in_sizes, int n_in,
                              void* d_out, int out_size, void* d_ws, size_t ws_size,
                              hipStream_t stream) {
    const float* x  = (const float*)d_in[0];
    const float* W1 = (const float*)d_in[1];
    const float* U1 = (const float*)d_in[2];
    const float* b1 = (const float*)d_in[3];
    const float* W2 = (const float*)d_in[4];
    const float* U2 = (const float*)d_in[5];
    const float* b2 = (const float*)d_in[6];
    float* out = (float*)d_out;

    if (ws_size >= XW_BYTES) {
        unsigned short* ws = (unsigned short*)d_ws;
        xw_prepass<<<dim3(16, 256), dim3(256), 0, stream>>>(x, W1, b1, ws);
        gru_persist<true><<<dim3(16), dim3(256), 0, stream>>>(
            x, W1, U1, b1, W2, U2, b2, ws, out);
    } else {
        gru_persist<false><<<dim3(16), dim3(256), 0, stream>>>(
            x, W1, U1, b1, W2, U2, b2, nullptr, out);
    }
}

// Round 6
// 1848.191 us; speedup vs baseline: 1.4043x; 1.0926x over previous
//
#include <hip/hip_runtime.h>

// Fused 2-layer GRU scan. B=256,T=1024,F=64,U=128.
// R1-R5 invariant: per-step global stream was lane-scattered (8B/lane at
// 512B+ stride) -> ~1500 serialized L1 transactions per CU-step = the
// ~2000-3000cyc floor no other change could move, + 2x HBM over-fetch.
// R6: xw workspace re-keyed to uint2 ws[t][rb][g][cg][lane] so BOTH the
// prepass store and the persist load are 512B-contiguous per wave (8
// transactions instead of 64). xw (201MB) also fits the 256MB L3.
// Persist structure unchanged from R5: 16 blocks x 256 thr (1 wave/SIMD,
// 512-reg budget), weights pinned resident, layer2 one step delayed,
// single LDS-only barrier per step.

#define TT 1024
#define FF 64
#define G3 384
#define XW_BYTES (1024ull * 384 * 256 * 2)

typedef __attribute__((ext_vector_type(8))) __bf16 bf16x8;
typedef __attribute__((ext_vector_type(4))) float f32x4;
typedef __attribute__((ext_vector_type(4))) int i32x4;

#define MFMA(a, b, c) __builtin_amdgcn_mfma_f32_16x16x32_bf16((a), (b), (c), 0, 0, 0)
#define BCAST(w) __builtin_bit_cast(bf16x8, w)

__device__ __forceinline__ float sigf(float x) {
    return __builtin_amdgcn_rcpf(1.0f + __expf(-x));
}

__device__ __forceinline__ void unpack4(uint2 v, float* o) {
    o[0] = __uint_as_float(v.x << 16);
    o[1] = __uint_as_float(v.x & 0xFFFF0000u);
    o[2] = __uint_as_float(v.y << 16);
    o[3] = __uint_as_float(v.y & 0xFFFF0000u);
}

// ---- prepass: ws uint2 index = ((t*16+rb)*3+g)*512 + cg*64 + lane ---------
// slot holds batch rows quad*4..+3 (C regs), unit col cg*16+lc, bf16x4 packed.
// Wave writes 64 consecutive uint2 = 512B contiguous per (g,cg).
__global__ void xw_prepass(
    const float* __restrict__ x, const float* __restrict__ W1,
    const float* __restrict__ b1, unsigned short* __restrict__ ws)
{
    const int tid = threadIdx.x, wave = tid >> 6, lane = tid & 63;
    const int quad = lane >> 4, lc = lane & 15;
    const int rb = blockIdx.x;              // row block (16 rows)
    const int t  = blockIdx.y * 4 + wave;   // time step

    const float* px = x + ((size_t)(rb * 16 + lc) * TT + t) * FF + quad * 8;
    f32x4 u0 = *(const f32x4*)px;
    f32x4 u1 = *(const f32x4*)(px + 4);
    f32x4 u2 = *(const f32x4*)(px + 32);
    f32x4 u3 = *(const f32x4*)(px + 36);
    bf16x8 xa0, xa1;
#pragma unroll
    for (int j = 0; j < 4; j++) {
        xa0[j] = (__bf16)u0[j]; xa0[j + 4] = (__bf16)u1[j];
        xa1[j] = (__bf16)u2[j]; xa1[j + 4] = (__bf16)u3[j];
    }

    uint2* wq = (uint2*)ws + ((size_t)t * 16 + rb) * 1536 + lane;
    for (int nt = 0; nt < 24; nt++) {
        const int g  = nt >> 3;
        const int cg = nt & 7;
        const int uc = cg * 16 + lc;
        const float bi = b1[g * 128 + uc];
        bf16x8 w0, w1v;
#pragma unroll
        for (int j = 0; j < 8; j++) {
            w0[j]  = (__bf16)W1[(quad * 8 + j) * G3 + g * 128 + uc];
            w1v[j] = (__bf16)W1[(32 + quad * 8 + j) * G3 + g * 128 + uc];
        }
        f32x4 acc = {bi, bi, bi, bi};
        acc = MFMA(xa0, w0, acc);
        acc = MFMA(xa1, w1v, acc);
        unsigned int s0 = __builtin_bit_cast(unsigned short, (__bf16)acc[0]);
        unsigned int s1 = __builtin_bit_cast(unsigned short, (__bf16)acc[1]);
        unsigned int s2 = __builtin_bit_cast(unsigned short, (__bf16)acc[2]);
        unsigned int s3 = __builtin_bit_cast(unsigned short, (__bf16)acc[3]);
        uint2 st;
        st.x = s0 | (s1 << 16);
        st.y = s2 | (s3 << 16);
        wq[(size_t)(g * 8 + cg) * 64] = st;   // 512B contiguous per wave
    }
}

// ---- persistent scan kernel -----------------------------------------------
template <bool PRE>
__global__ __launch_bounds__(256, 1) void gru_persist(
    const float* __restrict__ x,  const float* __restrict__ W1,
    const float* __restrict__ U1, const float* __restrict__ b1,
    const float* __restrict__ W2, const float* __restrict__ U2,
    const float* __restrict__ b2, const unsigned short* __restrict__ xw,
    float* __restrict__ out)
{
    const int tid  = threadIdx.x;
    const int wave = tid >> 6;          // 0..3
    const int lane = tid & 63;
    const int quad = lane >> 4;
    const int lc   = lane & 15;
    const int row0 = blockIdx.x * 16;

    __shared__ __align__(16) __bf16 h1s[2][16][136];
    __shared__ __align__(16) __bf16 h2s[2][16][136];
    for (int i = tid; i < 2 * 16 * 136; i += 256) {
        ((__bf16*)h1s)[i] = (__bf16)0.f;
        ((__bf16*)h2s)[i] = (__bf16)0.f;
    }

    // ---- weight B-frags: 2 column groups/wave, pinned resident ----
    i32x4 U1B[2][3][4], W2B[2][3][4], U2B[2][3][4];
    i32x4 W1B[2][3][2];
#pragma unroll
    for (int gg = 0; gg < 2; gg++) {
        const int col0 = wave * 32 + gg * 16 + lc;
#pragma unroll
        for (int g = 0; g < 3; g++) {
#pragma unroll
            for (int kt = 0; kt < 4; kt++) {
                bf16x8 a, b, c;
#pragma unroll
                for (int j = 0; j < 8; j++) {
                    int k = (kt * 32 + quad * 8 + j) * G3 + g * 128 + col0;
                    a[j] = (__bf16)U1[k];
                    b[j] = (__bf16)W2[k];
                    c[j] = (__bf16)U2[k];
                }
                U1B[gg][g][kt] = __builtin_bit_cast(i32x4, a);
                W2B[gg][g][kt] = __builtin_bit_cast(i32x4, b);
                U2B[gg][g][kt] = __builtin_bit_cast(i32x4, c);
            }
            if constexpr (!PRE) {
#pragma unroll
                for (int kt = 0; kt < 2; kt++) {
                    bf16x8 a;
#pragma unroll
                    for (int j = 0; j < 8; j++)
                        a[j] = (__bf16)W1[(kt * 32 + quad * 8 + j) * G3 + g * 128 + col0];
                    W1B[gg][g][kt] = __builtin_bit_cast(i32x4, a);
                }
            }
        }
    }
#pragma unroll
    for (int gg = 0; gg < 2; gg++)
#pragma unroll
        for (int g = 0; g < 3; g++)
#pragma unroll
            for (int kt = 0; kt < 4; kt++)
                asm volatile("" : "+v"(U1B[gg][g][kt]), "+v"(W2B[gg][g][kt]),
                                  "+v"(U2B[gg][g][kt]));
    if constexpr (!PRE) {
#pragma unroll
        for (int gg = 0; gg < 2; gg++)
#pragma unroll
            for (int g = 0; g < 3; g++)
#pragma unroll
                for (int kt = 0; kt < 2; kt++)
                    asm volatile("" : "+v"(W1B[gg][g][kt]));
    }

    // ---- biases (zero here; honored) ----
    float c1z[2], c1r[2], b1ih[2], b1rh[2], c2z[2], c2r[2], b2ih[2], b2rh[2];
#pragma unroll
    for (int gg = 0; gg < 2; gg++) {
        const int u = wave * 32 + gg * 16 + lc;
        c1z[gg]  = PRE ? b1[G3 + u] : b1[u] + b1[G3 + u];
        c1r[gg]  = PRE ? b1[G3 + 128 + u] : b1[128 + u] + b1[G3 + 128 + u];
        b1ih[gg] = b1[256 + u];
        b1rh[gg] = b1[G3 + 256 + u];
        c2z[gg]  = b2[u] + b2[G3 + u];
        c2r[gg]  = b2[128 + u] + b2[G3 + 128 + u];
        b2ih[gg] = b2[256 + u];
        b2rh[gg] = b2[G3 + 256 + u];
    }

    // ---- xw base: uint2 index = ((t*16+rb)*3+g)*512 + (wave*2+gg)*64 + lane
    // per (g,gg): wave reads 64 consecutive uint2 = 512B contiguous.
    const uint2* xqb = (const uint2*)xw + (size_t)blockIdx.x * 1536
                       + wave * 128 + lane;
    uint2 xwv[2][2][3];   // [parity][gg][gate]
    if constexpr (PRE) {
#pragma unroll
        for (int gg = 0; gg < 2; gg++)
#pragma unroll
            for (int g = 0; g < 3; g++) {
                xwv[0][gg][g] = xqb[(size_t)g * 512 + gg * 64];
                xwv[1][gg][g] = xqb[24576 + (size_t)g * 512 + gg * 64];
            }
    }
    const float* xrow = x + (size_t)(row0 + lc) * (TT * FF) + quad * 8;

    float h1c[2][4] = {{0,0,0,0},{0,0,0,0}};
    float h2c[2][4] = {{0,0,0,0},{0,0,0,0}};

    __syncthreads();

#define STEP(T, PAR)                                                           \
    {                                                                          \
        bf16x8 A1[4];                                                          \
        _Pragma("unroll") for (int kt = 0; kt < 4; kt++)                       \
            A1[kt] = *(const bf16x8*)&h1s[PAR ^ 1][lc][kt * 32 + quad * 8];    \
        float xz[2][4], xr[2][4], xh[2][4];                                    \
        bf16x8 xa0, xa1;                                                       \
        if constexpr (PRE) {                                                   \
            _Pragma("unroll") for (int gg = 0; gg < 2; gg++) {                 \
                unpack4(xwv[PAR][gg][0], xz[gg]);                              \
                unpack4(xwv[PAR][gg][1], xr[gg]);                              \
                unpack4(xwv[PAR][gg][2], xh[gg]);                              \
            }                                                                  \
            if ((T) + 2 < TT) {                                                \
                _Pragma("unroll") for (int gg = 0; gg < 2; gg++)               \
                    _Pragma("unroll") for (int g = 0; g < 3; g++)              \
                        xwv[PAR][gg][g] =                                      \
                            xqb[(size_t)((T) + 2) * 24576 + g * 512 + gg * 64];\
            }                                                                  \
        } else {                                                               \
            const float* px = xrow + (size_t)(T) * FF;                         \
            f32x4 u0 = *(const f32x4*)px;                                      \
            f32x4 u1 = *(const f32x4*)(px + 4);                                \
            f32x4 u2 = *(const f32x4*)(px + 32);                               \
            f32x4 u3 = *(const f32x4*)(px + 36);                               \
            _Pragma("unroll") for (int j = 0; j < 4; j++) {                    \
                xa0[j] = (__bf16)u0[j]; xa0[j + 4] = (__bf16)u1[j];            \
                xa1[j] = (__bf16)u2[j]; xa1[j + 4] = (__bf16)u3[j];            \
            }                                                                  \
        }                                                                      \
        f32x4 z1[2], r1[2], rh1[2], xh1[2];                                    \
        _Pragma("unroll") for (int gg = 0; gg < 2; gg++) {                     \
            z1[gg]  = (f32x4){c1z[gg], c1z[gg], c1z[gg], c1z[gg]};             \
            r1[gg]  = (f32x4){c1r[gg], c1r[gg], c1r[gg], c1r[gg]};             \
            rh1[gg] = (f32x4){b1rh[gg], b1rh[gg], b1rh[gg], b1rh[gg]};         \
            xh1[gg] = (f32x4){b1ih[gg], b1ih[gg], b1ih[gg], b1ih[gg]};         \
            if constexpr (PRE) {                                               \
                _Pragma("unroll") for (int i = 0; i < 4; i++) {                \
                    z1[gg][i] += xz[gg][i];                                    \
                    r1[gg][i] += xr[gg][i];                                    \
                }                                                              \
            } else {                                                           \
                z1[gg]  = MFMA(xa0, BCAST(W1B[gg][0][0]), z1[gg]);             \
                z1[gg]  = MFMA(xa1, BCAST(W1B[gg][0][1]), z1[gg]);             \
                r1[gg]  = MFMA(xa0, BCAST(W1B[gg][1][0]), r1[gg]);             \
                r1[gg]  = MFMA(xa1, BCAST(W1B[gg][1][1]), r1[gg]);             \
                xh1[gg] = MFMA(xa0, BCAST(W1B[gg][2][0]), xh1[gg]);            \
                xh1[gg] = MFMA(xa1, BCAST(W1B[gg][2][1]), xh1[gg]);            \
            }                                                                  \
        }                                                                      \
        _Pragma("unroll") for (int kt = 0; kt < 4; kt++)                       \
            _Pragma("unroll") for (int gg = 0; gg < 2; gg++) {                 \
                z1[gg]  = MFMA(A1[kt], BCAST(U1B[gg][0][kt]), z1[gg]);         \
                r1[gg]  = MFMA(A1[kt], BCAST(U1B[gg][1][kt]), r1[gg]);         \
                rh1[gg] = MFMA(A1[kt], BCAST(U1B[gg][2][kt]), rh1[gg]);        \
            }                                                                  \
        _Pragma("unroll") for (int gg = 0; gg < 2; gg++) {                     \
            const int u = wave * 32 + gg * 16 + lc;                            \
            _Pragma("unroll") for (int i = 0; i < 4; i++) {                    \
                float zf = sigf(z1[gg][i]);                                    \
                float rf = sigf(r1[gg][i]);                                    \
                float xhv = PRE ? xh[gg][i] : xh1[gg][i];                      \
                float hh = fmaxf(xhv + rf * rh1[gg][i], 0.f);                  \
                h1c[gg][i] = fmaf(zf, h1c[gg][i] - hh, hh);                    \
                h1s[PAR][quad * 4 + i][u] = (__bf16)h1c[gg][i];                \
            }                                                                  \
        }                                                                      \
        f32x4 z2[2], r2[2], xh2[2], rh2[2];                                    \
        _Pragma("unroll") for (int gg = 0; gg < 2; gg++) {                     \
            z2[gg]  = (f32x4){c2z[gg], c2z[gg], c2z[gg], c2z[gg]};             \
            r2[gg]  = (f32x4){c2r[gg], c2r[gg], c2r[gg], c2r[gg]};             \
            xh2[gg] = (f32x4){b2ih[gg], b2ih[gg], b2ih[gg], b2ih[gg]};         \
            rh2[gg] = (f32x4){b2rh[gg], b2rh[gg], b2rh[gg], b2rh[gg]};         \
        }                                                                      \
        _Pragma("unroll") for (int kt = 0; kt < 4; kt++)                       \
            _Pragma("unroll") for (int gg = 0; gg < 2; gg++) {                 \
                z2[gg]  = MFMA(A1[kt], BCAST(W2B[gg][0][kt]), z2[gg]);         \
                r2[gg]  = MFMA(A1[kt], BCAST(W2B[gg][1][kt]), r2[gg]);         \
                xh2[gg] = MFMA(A1[kt], BCAST(W2B[gg][2][kt]), xh2[gg]);        \
            }                                                                  \
        bf16x8 A2[4];                                                          \
        _Pragma("unroll") for (int kt = 0; kt < 4; kt++)                       \
            A2[kt] = *(const bf16x8*)&h2s[PAR][lc][kt * 32 + quad * 8];        \
        _Pragma("unroll") for (int kt = 0; kt < 4; kt++)                       \
            _Pragma("unroll") for (int gg = 0; gg < 2; gg++) {                 \
                z2[gg]  = MFMA(A2[kt], BCAST(U2B[gg][0][kt]), z2[gg]);         \
                r2[gg]  = MFMA(A2[kt], BCAST(U2B[gg][1][kt]), r2[gg]);         \
                rh2[gg] = MFMA(A2[kt], BCAST(U2B[gg][2][kt]), rh2[gg]);        \
            }                                                                  \
        if ((T) > 0) {                                                         \
            _Pragma("unroll") for (int gg = 0; gg < 2; gg++)                   \
                _Pragma("unroll") for (int i = 0; i < 4; i++) {                \
                    float zf = sigf(z2[gg][i]);                                \
                    float rf = sigf(r2[gg][i]);                                \
                    float hh = fmaxf(xh2[gg][i] + rf * rh2[gg][i], 0.f);       \
                    h2c[gg][i] = fmaf(zf, h2c[gg][i] - hh, hh);                \
                }                                                              \
        }                                                                      \
        _Pragma("unroll") for (int gg = 0; gg < 2; gg++) {                     \
            const int u = wave * 32 + gg * 16 + lc;                            \
            _Pragma("unroll") for (int i = 0; i < 4; i++)                      \
                h2s[PAR ^ 1][quad * 4 + i][u] = (__bf16)h2c[gg][i];            \
        }                                                                      \
        asm volatile("s_waitcnt lgkmcnt(0)\n\ts_barrier" ::: "memory");        \
    }

    for (int t = 0; t < TT; t += 2) {
        STEP(t, 0)
        STEP(t + 1, 1)
    }
#undef STEP

    // Epilogue: h2(TT-1) from h1(TT-1) (h1s[1]) and h2(TT-2) (h2s[0])
    {
        f32x4 z2[2], r2[2], xh2[2], rh2[2];
#pragma unroll
        for (int gg = 0; gg < 2; gg++) {
            z2[gg]  = (f32x4){c2z[gg], c2z[gg], c2z[gg], c2z[gg]};
            r2[gg]  = (f32x4){c2r[gg], c2r[gg], c2r[gg], c2r[gg]};
            xh2[gg] = (f32x4){b2ih[gg], b2ih[gg], b2ih[gg], b2ih[gg]};
            rh2[gg] = (f32x4){b2rh[gg], b2rh[gg], b2rh[gg], b2rh[gg]};
        }
#pragma unroll
        for (int kt = 0; kt < 4; kt++) {
            bf16x8 a1 = *(const bf16x8*)&h1s[1][lc][kt * 32 + quad * 8];
            bf16x8 a2 = *(const bf16x8*)&h2s[0][lc][kt * 32 + quad * 8];
#pragma unroll
            for (int gg = 0; gg < 2; gg++) {
                z2[gg]  = MFMA(a1, BCAST(W2B[gg][0][kt]), z2[gg]);
                r2[gg]  = MFMA(a1, BCAST(W2B[gg][1][kt]), r2[gg]);
                xh2[gg] = MFMA(a1, BCAST(W2B[gg][2][kt]), xh2[gg]);
                z2[gg]  = MFMA(a2, BCAST(U2B[gg][0][kt]), z2[gg]);
                r2[gg]  = MFMA(a2, BCAST(U2B[gg][1][kt]), r2[gg]);
                rh2[gg] = MFMA(a2, BCAST(U2B[gg][2][kt]), rh2[gg]);
            }
        }
#pragma unroll
        for (int gg = 0; gg < 2; gg++)
#pragma unroll
            for (int i = 0; i < 4; i++) {
                float zf = sigf(z2[gg][i]);
                float rf = sigf(r2[gg][i]);
                float hh = fmaxf(xh2[gg][i] + rf * rh2[gg][i], 0.f);
                h2c[gg][i] = fmaf(zf, h2c[gg][i] - hh, hh);
            }
    }

    // out = [x = h2(T-1), state1 = h1(T-1), state2 = h2(T-1)]
#pragma unroll
    for (int gg = 0; gg < 2; gg++) {
        const int u = wave * 32 + gg * 16 + lc;
#pragma unroll
        for (int i = 0; i < 4; i++) {
            int r = row0 + quad * 4 + i;
            out[(size_t)r * 128 + u]         = h2c[gg][i];
            out[32768 + (size_t)r * 128 + u] = h1c[gg][i];
            out[65536 + (size_t)r * 128 + u] = h2c[gg][i];
        }
    }
}

extern "C" void kernel_launch(void* const* d_in, const int* in_sizes, int n_in,
                              void* d_out, int out_size, void* d_ws, size_t ws_size,
                              hipStream_t stream) {
    const float* x  = (const float*)d_in[0];
    const float* W1 = (const float*)d_in[1];
    const float* U1 = (const float*)d_in[2];
    const float* b1 = (const float*)d_in[3];
    const float* W2 = (const float*)d_in[4];
    const float* U2 = (const float*)d_in[5];
    const float* b2 = (const float*)d_in[6];
    float* out = (float*)d_out;

    if (ws_size >= XW_BYTES) {
        unsigned short* ws = (unsigned short*)d_ws;
        xw_prepass<<<dim3(16, 256), dim3(256), 0, stream>>>(x, W1, b1, ws);
        gru_persist<true><<<dim3(16), dim3(256), 0, stream>>>(
            x, W1, U1, b1, W2, U2, b2, ws, out);
    } else {
        gru_persist<false><<<dim3(16), dim3(256), 0, stream>>>(
            x, W1, U1, b1, W2, U2, b2, nullptr, out);
    }
}

// Round 7
// 1672.574 us; speedup vs baseline: 1.5517x; 1.1050x over previous
//
#include <hip/hip_runtime.h>

// Fused 2-layer GRU scan. B=256,T=1024,F=64,U=128.
// R6 post-mortem: active CUs are ISSUE-saturated (VALU 58% + MFMA 29%), and
// VALU inst count is ~3x what the source accounts for => AGPR<->VGPR copy
// churn: "+v" pins forced ArchVGPR class on a 288-reg weight set that cannot
// fit the 256 arch-VGPR file, so every MFMA B-use paid v_accvgpr_read x4.
// R7: weights pinned by CLASS into the AGPR file ("+a", 240 regs) except one
// 48-reg slice kept "+v"; gfx950 MFMA reads B directly from AGPR -> no loop
// copies. Also: recurrent z/r biases folded into the xw prepass so z1/r1
// init directly from the unpacked xw (saves ~32 VALU/step).
// Structure otherwise = R6: 16 blocks x 256 thr (1 wave/SIMD), xw stream
// coalesced (512B/wave chunks), layer2 one step delayed, single LDS-only
// barrier per step.

#define TT 1024
#define FF 64
#define G3 384
#define XW_BYTES (1024ull * 384 * 256 * 2)

typedef __attribute__((ext_vector_type(8))) __bf16 bf16x8;
typedef __attribute__((ext_vector_type(4))) float f32x4;
typedef __attribute__((ext_vector_type(4))) int i32x4;

#define MFMA(a, b, c) __builtin_amdgcn_mfma_f32_16x16x32_bf16((a), (b), (c), 0, 0, 0)
#define BCAST(w) __builtin_bit_cast(bf16x8, w)

__device__ __forceinline__ float sigf(float x) {
    return __builtin_amdgcn_rcpf(1.0f + __expf(-x));
}

__device__ __forceinline__ f32x4 unpackv(uint2 v) {
    f32x4 o;
    o[0] = __uint_as_float(v.x << 16);
    o[1] = __uint_as_float(v.x & 0xFFFF0000u);
    o[2] = __uint_as_float(v.y << 16);
    o[3] = __uint_as_float(v.y & 0xFFFF0000u);
    return o;
}

// ---- prepass: ws uint2 index = ((t*16+rb)*3+g)*512 + cg*64 + lane ---------
// slot holds batch rows quad*4..+3, unit col cg*16+lc, bf16x4 packed.
// For gates z,r BOTH input and recurrent biases are folded here; for gate h
// only the input bias (recurrent b_rh must stay separate for r*rh).
__global__ void xw_prepass(
    const float* __restrict__ x, const float* __restrict__ W1,
    const float* __restrict__ b1, unsigned short* __restrict__ ws)
{
    const int tid = threadIdx.x, wave = tid >> 6, lane = tid & 63;
    const int quad = lane >> 4, lc = lane & 15;
    const int rb = blockIdx.x;              // row block (16 rows)
    const int t  = blockIdx.y * 4 + wave;   // time step

    const float* px = x + ((size_t)(rb * 16 + lc) * TT + t) * FF + quad * 8;
    f32x4 u0 = *(const f32x4*)px;
    f32x4 u1 = *(const f32x4*)(px + 4);
    f32x4 u2 = *(const f32x4*)(px + 32);
    f32x4 u3 = *(const f32x4*)(px + 36);
    bf16x8 xa0, xa1;
#pragma unroll
    for (int j = 0; j < 4; j++) {
        xa0[j] = (__bf16)u0[j]; xa0[j + 4] = (__bf16)u1[j];
        xa1[j] = (__bf16)u2[j]; xa1[j + 4] = (__bf16)u3[j];
    }

    uint2* wq = (uint2*)ws + ((size_t)t * 16 + rb) * 1536 + lane;
    for (int nt = 0; nt < 24; nt++) {
        const int g  = nt >> 3;
        const int cg = nt & 7;
        const int uc = cg * 16 + lc;
        float bi = b1[g * 128 + uc];
        if (g < 2) bi += b1[G3 + g * 128 + uc];   // fold recurrent bias (z,r)
        bf16x8 w0, w1v;
#pragma unroll
        for (int j = 0; j < 8; j++) {
            w0[j]  = (__bf16)W1[(quad * 8 + j) * G3 + g * 128 + uc];
            w1v[j] = (__bf16)W1[(32 + quad * 8 + j) * G3 + g * 128 + uc];
        }
        f32x4 acc = {bi, bi, bi, bi};
        acc = MFMA(xa0, w0, acc);
        acc = MFMA(xa1, w1v, acc);
        unsigned int s0 = __builtin_bit_cast(unsigned short, (__bf16)acc[0]);
        unsigned int s1 = __builtin_bit_cast(unsigned short, (__bf16)acc[1]);
        unsigned int s2 = __builtin_bit_cast(unsigned short, (__bf16)acc[2]);
        unsigned int s3 = __builtin_bit_cast(unsigned short, (__bf16)acc[3]);
        uint2 st;
        st.x = s0 | (s1 << 16);
        st.y = s2 | (s3 << 16);
        wq[(size_t)(g * 8 + cg) * 64] = st;   // 512B contiguous per wave
    }
}

// ---- persistent scan kernel -----------------------------------------------
template <bool PRE>
__global__ __launch_bounds__(256, 1) void gru_persist(
    const float* __restrict__ x,  const float* __restrict__ W1,
    const float* __restrict__ U1, const float* __restrict__ b1,
    const float* __restrict__ W2, const float* __restrict__ U2,
    const float* __restrict__ b2, const unsigned short* __restrict__ xw,
    float* __restrict__ out)
{
    const int tid  = threadIdx.x;
    const int wave = tid >> 6;          // 0..3
    const int lane = tid & 63;
    const int quad = lane >> 4;
    const int lc   = lane & 15;
    const int row0 = blockIdx.x * 16;

    __shared__ __align__(16) __bf16 h1s[2][16][136];
    __shared__ __align__(16) __bf16 h2s[2][16][136];
    for (int i = tid; i < 2 * 16 * 136; i += 256) {
        ((__bf16*)h1s)[i] = (__bf16)0.f;
        ((__bf16*)h2s)[i] = (__bf16)0.f;
    }

    // ---- weight B-frags: 2 column groups/wave ----
    i32x4 U1B[2][3][4], W2B[2][3][4], U2B[2][3][4];
    i32x4 W1B[2][3][2];
#pragma unroll
    for (int gg = 0; gg < 2; gg++) {
        const int col0 = wave * 32 + gg * 16 + lc;
#pragma unroll
        for (int g = 0; g < 3; g++) {
#pragma unroll
            for (int kt = 0; kt < 4; kt++) {
                bf16x8 a, b, c;
#pragma unroll
                for (int j = 0; j < 8; j++) {
                    int k = (kt * 32 + quad * 8 + j) * G3 + g * 128 + col0;
                    a[j] = (__bf16)U1[k];
                    b[j] = (__bf16)W2[k];
                    c[j] = (__bf16)U2[k];
                }
                U1B[gg][g][kt] = __builtin_bit_cast(i32x4, a);
                W2B[gg][g][kt] = __builtin_bit_cast(i32x4, b);
                U2B[gg][g][kt] = __builtin_bit_cast(i32x4, c);
            }
            if constexpr (!PRE) {
#pragma unroll
                for (int kt = 0; kt < 2; kt++) {
                    bf16x8 a;
#pragma unroll
                    for (int j = 0; j < 8; j++)
                        a[j] = (__bf16)W1[(kt * 32 + quad * 8 + j) * G3 + g * 128 + col0];
                    W1B[gg][g][kt] = __builtin_bit_cast(i32x4, a);
                }
            }
        }
    }
    // CLASS pins: 60 frags (240 regs) into the AGPR file -- MFMA reads B
    // directly from AGPR on gfx950, so the step loop has ZERO accvgpr copies.
    // U1B[1] (12 frags, 48 regs) stays ArchVGPR to respect the 256-AGPR cap.
#pragma unroll
    for (int g = 0; g < 3; g++)
#pragma unroll
        for (int kt = 0; kt < 4; kt++) {
            asm volatile("" : "+a"(W2B[0][g][kt]), "+a"(W2B[1][g][kt]),
                              "+a"(U2B[0][g][kt]), "+a"(U2B[1][g][kt]),
                              "+a"(U1B[0][g][kt]));
            asm volatile("" : "+v"(U1B[1][g][kt]));
        }
    if constexpr (!PRE) {
#pragma unroll
        for (int gg = 0; gg < 2; gg++)
#pragma unroll
            for (int g = 0; g < 3; g++)
#pragma unroll
                for (int kt = 0; kt < 2; kt++)
                    asm volatile("" : "+v"(W1B[gg][g][kt]));
    }

    // ---- biases (zero here; honored) ----
    float c1z[2], c1r[2], b1ih[2], b1rh[2], c2z[2], c2r[2], b2ih[2], b2rh[2];
#pragma unroll
    for (int gg = 0; gg < 2; gg++) {
        const int u = wave * 32 + gg * 16 + lc;
        c1z[gg]  = b1[u] + b1[G3 + u];              // used only when !PRE
        c1r[gg]  = b1[128 + u] + b1[G3 + 128 + u];  // used only when !PRE
        b1ih[gg] = b1[256 + u];
        b1rh[gg] = b1[G3 + 256 + u];
        c2z[gg]  = b2[u] + b2[G3 + u];
        c2r[gg]  = b2[128 + u] + b2[G3 + 128 + u];
        b2ih[gg] = b2[256 + u];
        b2rh[gg] = b2[G3 + 256 + u];
    }

    // ---- xw base: uint2 index = ((t*16+rb)*3+g)*512 + (wave*2+gg)*64 + lane
    const uint2* xqb = (const uint2*)xw + (size_t)blockIdx.x * 1536
                       + wave * 128 + lane;
    uint2 xwv[2][2][3];   // [parity][gg][gate]
    if constexpr (PRE) {
#pragma unroll
        for (int gg = 0; gg < 2; gg++)
#pragma unroll
            for (int g = 0; g < 3; g++) {
                xwv[0][gg][g] = xqb[(size_t)g * 512 + gg * 64];
                xwv[1][gg][g] = xqb[24576 + (size_t)g * 512 + gg * 64];
            }
    }
    const float* xrow = x + (size_t)(row0 + lc) * (TT * FF) + quad * 8;

    float h1c[2][4] = {{0,0,0,0},{0,0,0,0}};
    float h2c[2][4] = {{0,0,0,0},{0,0,0,0}};

    __syncthreads();

#define STEP(T, PAR)                                                           \
    {                                                                          \
        bf16x8 A1[4];                                                          \
        _Pragma("unroll") for (int kt = 0; kt < 4; kt++)                       \
            A1[kt] = *(const bf16x8*)&h1s[PAR ^ 1][lc][kt * 32 + quad * 8];    \
        f32x4 z1[2], r1[2], rh1[2], xh1[2];                                    \
        bf16x8 xa0, xa1;                                                       \
        if constexpr (PRE) {                                                   \
            _Pragma("unroll") for (int gg = 0; gg < 2; gg++) {                 \
                z1[gg]  = unpackv(xwv[PAR][gg][0]);  /* xz incl. both biases */\
                r1[gg]  = unpackv(xwv[PAR][gg][1]);                            \
                xh1[gg] = unpackv(xwv[PAR][gg][2]);  /* xh incl. input bias */ \
                rh1[gg] = (f32x4){b1rh[gg], b1rh[gg], b1rh[gg], b1rh[gg]};     \
            }                                                                  \
            if ((T) + 2 < TT) {                                                \
                _Pragma("unroll") for (int gg = 0; gg < 2; gg++)               \
                    _Pragma("unroll") for (int g = 0; g < 3; g++)              \
                        xwv[PAR][gg][g] =                                      \
                            xqb[(size_t)((T) + 2) * 24576 + g * 512 + gg * 64];\
            }                                                                  \
        } else {                                                               \
            const float* px = xrow + (size_t)(T) * FF;                         \
            f32x4 u0 = *(const f32x4*)px;                                      \
            f32x4 u1 = *(const f32x4*)(px + 4);                                \
            f32x4 u2 = *(const f32x4*)(px + 32);                               \
            f32x4 u3 = *(const f32x4*)(px + 36);                               \
            _Pragma("unroll") for (int j = 0; j < 4; j++) {                    \
                xa0[j] = (__bf16)u0[j]; xa0[j + 4] = (__bf16)u1[j];            \
                xa1[j] = (__bf16)u2[j]; xa1[j + 4] = (__bf16)u3[j];            \
            }                                                                  \
            _Pragma("unroll") for (int gg = 0; gg < 2; gg++) {                 \
                z1[gg]  = (f32x4){c1z[gg], c1z[gg], c1z[gg], c1z[gg]};         \
                r1[gg]  = (f32x4){c1r[gg], c1r[gg], c1r[gg], c1r[gg]};         \
                rh1[gg] = (f32x4){b1rh[gg], b1rh[gg], b1rh[gg], b1rh[gg]};     \
                xh1[gg] = (f32x4){b1ih[gg], b1ih[gg], b1ih[gg], b1ih[gg]};     \
                z1[gg]  = MFMA(xa0, BCAST(W1B[gg][0][0]), z1[gg]);             \
                z1[gg]  = MFMA(xa1, BCAST(W1B[gg][0][1]), z1[gg]);             \
                r1[gg]  = MFMA(xa0, BCAST(W1B[gg][1][0]), r1[gg]);             \
                r1[gg]  = MFMA(xa1, BCAST(W1B[gg][1][1]), r1[gg]);             \
                xh1[gg] = MFMA(xa0, BCAST(W1B[gg][2][0]), xh1[gg]);            \
                xh1[gg] = MFMA(xa1, BCAST(W1B[gg][2][1]), xh1[gg]);            \
            }                                                                  \
        }                                                                      \
        _Pragma("unroll") for (int kt = 0; kt < 4; kt++)                       \
            _Pragma("unroll") for (int gg = 0; gg < 2; gg++) {                 \
                z1[gg]  = MFMA(A1[kt], BCAST(U1B[gg][0][kt]), z1[gg]);         \
                r1[gg]  = MFMA(A1[kt], BCAST(U1B[gg][1][kt]), r1[gg]);         \
                rh1[gg] = MFMA(A1[kt], BCAST(U1B[gg][2][kt]), rh1[gg]);        \
            }                                                                  \
        _Pragma("unroll") for (int gg = 0; gg < 2; gg++) {                     \
            const int u = wave * 32 + gg * 16 + lc;                            \
            _Pragma("unroll") for (int i = 0; i < 4; i++) {                    \
                float zf = sigf(z1[gg][i]);                                    \
                float rf = sigf(r1[gg][i]);                                    \
                float hh = fmaxf(xh1[gg][i] + rf * rh1[gg][i], 0.f);           \
                h1c[gg][i] = fmaf(zf, h1c[gg][i] - hh, hh);                    \
                h1s[PAR][quad * 4 + i][u] = (__bf16)h1c[gg][i];                \
            }                                                                  \
        }                                                                      \
        f32x4 z2[2], r2[2], xh2[2], rh2[2];                                    \
        _Pragma("unroll") for (int gg = 0; gg < 2; gg++) {                     \
            z2[gg]  = (f32x4){c2z[gg], c2z[gg], c2z[gg], c2z[gg]};             \
            r2[gg]  = (f32x4){c2r[gg], c2r[gg], c2r[gg], c2r[gg]};             \
            xh2[gg] = (f32x4){b2ih[gg], b2ih[gg], b2ih[gg], b2ih[gg]};         \
            rh2[gg] = (f32x4){b2rh[gg], b2rh[gg], b2rh[gg], b2rh[gg]};         \
        }                                                                      \
        _Pragma("unroll") for (int kt = 0; kt < 4; kt++)                       \
            _Pragma("unroll") for (int gg = 0; gg < 2; gg++) {                 \
                z2[gg]  = MFMA(A1[kt], BCAST(W2B[gg][0][kt]), z2[gg]);         \
                r2[gg]  = MFMA(A1[kt], BCAST(W2B[gg][1][kt]), r2[gg]);         \
                xh2[gg] = MFMA(A1[kt], BCAST(W2B[gg][2][kt]), xh2[gg]);        \
            }                                                                  \
        bf16x8 A2[4];                                                          \
        _Pragma("unroll") for (int kt = 0; kt < 4; kt++)                       \
            A2[kt] = *(const bf16x8*)&h2s[PAR][lc][kt * 32 + quad * 8];        \
        _Pragma("unroll") for (int kt = 0; kt < 4; kt++)                       \
            _Pragma("unroll") for (int gg = 0; gg < 2; gg++) {                 \
                z2[gg]  = MFMA(A2[kt], BCAST(U2B[gg][0][kt]), z2[gg]);         \
                r2[gg]  = MFMA(A2[kt], BCAST(U2B[gg][1][kt]), r2[gg]);         \
                rh2[gg] = MFMA(A2[kt], BCAST(U2B[gg][2][kt]), rh2[gg]);        \
            }                                                                  \
        if ((T) > 0) {                                                         \
            _Pragma("unroll") for (int gg = 0; gg < 2; gg++)                   \
                _Pragma("unroll") for (int i = 0; i < 4; i++) {                \
                    float zf = sigf(z2[gg][i]);                                \
                    float rf = sigf(r2[gg][i]);                                \
                    float hh = fmaxf(xh2[gg][i] + rf * rh2[gg][i], 0.f);       \
                    h2c[gg][i] = fmaf(zf, h2c[gg][i] - hh, hh);                \
                }                                                              \
        }                                                                      \
        _Pragma("unroll") for (int gg = 0; gg < 2; gg++) {                     \
            const int u = wave * 32 + gg * 16 + lc;                            \
            _Pragma("unroll") for (int i = 0; i < 4; i++)                      \
                h2s[PAR ^ 1][quad * 4 + i][u] = (__bf16)h2c[gg][i];            \
        }                                                                      \
        asm volatile("s_waitcnt lgkmcnt(0)\n\ts_barrier" ::: "memory");        \
    }

    for (int t = 0; t < TT; t += 2) {
        STEP(t, 0)
        STEP(t + 1, 1)
    }
#undef STEP

    // Epilogue: h2(TT-1) from h1(TT-1) (h1s[1]) and h2(TT-2) (h2s[0])
    {
        f32x4 z2[2], r2[2], xh2[2], rh2[2];
#pragma unroll
        for (int gg = 0; gg < 2; gg++) {
            z2[gg]  = (f32x4){c2z[gg], c2z[gg], c2z[gg], c2z[gg]};
            r2[gg]  = (f32x4){c2r[gg], c2r[gg], c2r[gg], c2r[gg]};
            xh2[gg] = (f32x4){b2ih[gg], b2ih[gg], b2ih[gg], b2ih[gg]};
            rh2[gg] = (f32x4){b2rh[gg], b2rh[gg], b2rh[gg], b2rh[gg]};
        }
#pragma unroll
        for (int kt = 0; kt < 4; kt++) {
            bf16x8 a1 = *(const bf16x8*)&h1s[1][lc][kt * 32 + quad * 8];
            bf16x8 a2 = *(const bf16x8*)&h2s[0][lc][kt * 32 + quad * 8];
#pragma unroll
            for (int gg = 0; gg < 2; gg++) {
                z2[gg]  = MFMA(a1, BCAST(W2B[gg][0][kt]), z2[gg]);
                r2[gg]  = MFMA(a1, BCAST(W2B[gg][1][kt]), r2[gg]);
                xh2[gg] = MFMA(a1, BCAST(W2B[gg][2][kt]), xh2[gg]);
                z2[gg]  = MFMA(a2, BCAST(U2B[gg][0][kt]), z2[gg]);
                r2[gg]  = MFMA(a2, BCAST(U2B[gg][1][kt]), r2[gg]);
                rh2[gg] = MFMA(a2, BCAST(U2B[gg][2][kt]), rh2[gg]);
            }
        }
#pragma unroll
        for (int gg = 0; gg < 2; gg++)
#pragma unroll
            for (int i = 0; i < 4; i++) {
                float zf = sigf(z2[gg][i]);
                float rf = sigf(r2[gg][i]);
                float hh = fmaxf(xh2[gg][i] + rf * rh2[gg][i], 0.f);
                h2c[gg][i] = fmaf(zf, h2c[gg][i] - hh, hh);
            }
    }

    // out = [x = h2(T-1), state1 = h1(T-1), state2 = h2(T-1)]
#pragma unroll
    for (int gg = 0; gg < 2; gg++) {
        const int u = wave * 32 + gg * 16 + lc;
#pragma unroll
        for (int i = 0; i < 4; i++) {
            int r = row0 + quad * 4 + i;
            out[(size_t)r * 128 + u]         = h2c[gg][i];
            out[32768 + (size_t)r * 128 + u] = h1c[gg][i];
            out[65536 + (size_t)r * 128 + u] = h2c[gg][i];
        }
    }
}

extern "C" void kernel_launch(void* const* d_in, const int* in_sizes, int n_in,
                              void* d_out, int out_size, void* d_ws, size_t ws_size,
                              hipStream_t stream) {
    const float* x  = (const float*)d_in[0];
    const float* W1 = (const float*)d_in[1];
    const float* U1 = (const float*)d_in[2];
    const float* b1 = (const float*)d_in[3];
    const float* W2 = (const float*)d_in[4];
    const float* U2 = (const float*)d_in[5];
    const float* b2 = (const float*)d_in[6];
    float* out = (float*)d_out;

    if (ws_size >= XW_BYTES) {
        unsigned short* ws = (unsigned short*)d_ws;
        xw_prepass<<<dim3(16, 256), dim3(256), 0, stream>>>(x, W1, b1, ws);
        gru_persist<true><<<dim3(16), dim3(256), 0, stream>>>(
            x, W1, U1, b1, W2, U2, b2, ws, out);
    } else {
        gru_persist<false><<<dim3(16), dim3(256), 0, stream>>>(
            x, W1, U1, b1, W2, U2, b2, nullptr, out);
    }
}